// Round 2
// baseline (875.865 us; speedup 1.0000x reference)
//
#include <hip/hip_runtime.h>
#include <hip/hip_bf16.h>
#include <math.h>

// ---------------- degree / dinv ----------------

__global__ void init_ones_kernel(float* p, int n) {
    int i = blockIdx.x * blockDim.x + threadIdx.x;
    if (i < n) p[i] = 1.0f;
}

__global__ void count_deg_kernel(const int* __restrict__ dst, float* deg, int E) {
    int i = blockIdx.x * blockDim.x + threadIdx.x;
    if (i < E) atomicAdd(&deg[dst[i]], 1.0f);
}

__global__ void rsqrt_kernel(float* p, int n) {
    int i = blockIdx.x * blockDim.x + threadIdx.x;
    if (i < n) p[i] = rsqrtf(p[i]);
}

// ---------------- fp32 tiled GEMM: C[M,N] = A[M,K] @ B[K,N] ----------------
// BM=BN=64, BK=16, 256 threads, 4x4 microtile. K assumed multiple of 16,
// A rows 16B-aligned loads (K multiple of 4).

__global__ __launch_bounds__(256) void sgemm_kernel(const float* __restrict__ A,
                                                    const float* __restrict__ B,
                                                    float* __restrict__ C,
                                                    int M, int N, int K) {
    const int BM = 64, BN = 64, BK = 16;
    __shared__ float As[BK][BM + 1];
    __shared__ float Bs[BK][BN];

    int tid = threadIdx.x;
    int tx = tid & 15;    // 0..15 -> 4 cols each
    int ty = tid >> 4;    // 0..15 -> 4 rows each
    int bm0 = blockIdx.x * BM;
    int bn0 = blockIdx.y * BN;

    int arow = tid >> 2;        // 0..63
    int ak   = (tid & 3) * 4;   // 0,4,8,12
    int brow = tid >> 4;        // 0..15
    int bcol = (tid & 15) * 4;  // 0..60

    float acc[4][4] = {};

    for (int k0 = 0; k0 < K; k0 += BK) {
        // A tile (transposed into LDS)
        int grow = bm0 + arow;
        if (grow < M) {
            const float4 v = *reinterpret_cast<const float4*>(A + (size_t)grow * K + k0 + ak);
            As[ak + 0][arow] = v.x;
            As[ak + 1][arow] = v.y;
            As[ak + 2][arow] = v.z;
            As[ak + 3][arow] = v.w;
        } else {
            As[ak + 0][arow] = 0.0f;
            As[ak + 1][arow] = 0.0f;
            As[ak + 2][arow] = 0.0f;
            As[ak + 3][arow] = 0.0f;
        }
        // B tile
        {
            const float* bp = B + (size_t)(k0 + brow) * N + bn0 + bcol;
#pragma unroll
            for (int j = 0; j < 4; ++j)
                Bs[brow][bcol + j] = (bn0 + bcol + j < N) ? bp[j] : 0.0f;
        }
        __syncthreads();

#pragma unroll
        for (int k = 0; k < BK; ++k) {
            float a[4], b[4];
#pragma unroll
            for (int i = 0; i < 4; ++i) a[i] = As[k][ty * 4 + i];
#pragma unroll
            for (int j = 0; j < 4; ++j) b[j] = Bs[k][tx * 4 + j];
#pragma unroll
            for (int i = 0; i < 4; ++i)
#pragma unroll
                for (int j = 0; j < 4; ++j) acc[i][j] += a[i] * b[j];
        }
        __syncthreads();
    }

#pragma unroll
    for (int i = 0; i < 4; ++i) {
        int r = bm0 + ty * 4 + i;
        if (r >= M) continue;
#pragma unroll
        for (int j = 0; j < 4; ++j) {
            int c = bn0 + tx * 4 + j;
            if (c < N) C[(size_t)r * N + c] = acc[i][j];
        }
    }
}

// ---------------- self-loop init: agg = xw * dinv[node]^2 ----------------

template <int LOGF>
__global__ void self_init_kernel(const float* __restrict__ xw, const float* __restrict__ dinv,
                                 float* __restrict__ agg, int total) {
    for (int i = blockIdx.x * blockDim.x + threadIdx.x; i < total;
         i += gridDim.x * blockDim.x) {
        int node = i >> LOGF;
        float di = dinv[node];
        agg[i] = xw[i] * di * di;
    }
}

// ---------------- edge scatter: agg[dst] += xw[src] * dinv[src]*dinv[dst] ----------------

template <int LOGF>
__global__ void scatter_kernel(const float* __restrict__ xw, const int* __restrict__ src,
                               const int* __restrict__ dst, const float* __restrict__ dinv,
                               float* __restrict__ agg, int E) {
    const int F = 1 << LOGF;
    const long long total = (long long)E << LOGF;
    for (long long i = (long long)blockIdx.x * blockDim.x + threadIdx.x; i < total;
         i += (long long)gridDim.x * blockDim.x) {
        int e = (int)(i >> LOGF);
        int f = (int)(i & (F - 1));
        int s = src[e];
        int d = dst[e];
        float c = dinv[s] * dinv[d];
        atomicAdd(&agg[((size_t)d << LOGF) + f], xw[((size_t)s << LOGF) + f] * c);
    }
}

// ---------------- bias + relu ----------------

template <int LOGF>
__global__ void bias_relu_kernel(const float* __restrict__ agg, const float* __restrict__ bias,
                                 float* __restrict__ out, int total) {
    const int F = 1 << LOGF;
    for (int i = blockIdx.x * blockDim.x + threadIdx.x; i < total;
         i += gridDim.x * blockDim.x) {
        out[i] = fmaxf(agg[i] + bias[i & (F - 1)], 0.0f);
    }
}

// ---------------- launch ----------------

extern "C" void kernel_launch(void* const* d_in, const int* in_sizes, int n_in,
                              void* d_out, int out_size, void* d_ws, size_t ws_size,
                              hipStream_t stream) {
    const float* x = (const float*)d_in[0];
    const int* edge = (const int*)d_in[1];     // int32 on device (harness demotes int64)
    const float* W1 = (const float*)d_in[2];
    const float* b1 = (const float*)d_in[3];
    const float* W2 = (const float*)d_in[4];
    const float* b2 = (const float*)d_in[5];
    const float* W3 = (const float*)d_in[6];
    const float* b3 = (const float*)d_in[7];

    const int C_IN = 256, H1 = 128, H2 = 64, H3 = 32;
    const int N = in_sizes[0] / C_IN;   // 100000
    const int E = in_sizes[1] / 2;      // 800000
    const int* srcp = edge;
    const int* dstp = edge + E;

    char* ws = (char*)d_ws;
    float* dinv = (float*)ws;
    size_t off = (((size_t)N * 4) + 255) & ~(size_t)255;
    float* buf0 = (float*)(ws + off);
    float* buf1 = buf0 + (size_t)N * H1;
    float* out = (float*)d_out;

    // ---- degree / dinv (shared by all layers) ----
    init_ones_kernel<<<(N + 255) / 256, 256, 0, stream>>>(dinv, N);
    count_deg_kernel<<<(E + 255) / 256, 256, 0, stream>>>(dstp, dinv, E);
    rsqrt_kernel<<<(N + 255) / 256, 256, 0, stream>>>(dinv, N);

    const int EW_BLOCKS = 4096;    // elementwise grid-stride
    const int SC_BLOCKS = 8192;    // scatter grid-stride

    // ---- layer 1: 256 -> 128 ----
    {
        dim3 grid((N + 63) / 64, (H1 + 63) / 64);
        sgemm_kernel<<<grid, 256, 0, stream>>>(x, W1, buf0, N, H1, C_IN);
        int total = N * H1;
        self_init_kernel<7><<<EW_BLOCKS, 256, 0, stream>>>(buf0, dinv, buf1, total);
        scatter_kernel<7><<<SC_BLOCKS, 256, 0, stream>>>(buf0, srcp, dstp, dinv, buf1, E);
        bias_relu_kernel<7><<<EW_BLOCKS, 256, 0, stream>>>(buf1, b1, buf0, total);  // h1 -> buf0
    }
    // ---- layer 2: 128 -> 64 ----
    {
        dim3 grid((N + 63) / 64, (H2 + 63) / 64);
        sgemm_kernel<<<grid, 256, 0, stream>>>(buf0, W2, buf1, N, H2, H1);
        int total = N * H2;
        self_init_kernel<6><<<EW_BLOCKS, 256, 0, stream>>>(buf1, dinv, buf0, total);
        scatter_kernel<6><<<SC_BLOCKS, 256, 0, stream>>>(buf1, srcp, dstp, dinv, buf0, E);
        bias_relu_kernel<6><<<EW_BLOCKS, 256, 0, stream>>>(buf0, b2, buf1, total);  // h2 -> buf1
    }
    // ---- layer 3: 64 -> 32 ----
    {
        dim3 grid((N + 63) / 64, (H3 + 63) / 64);
        sgemm_kernel<<<grid, 256, 0, stream>>>(buf1, W3, buf0, N, H3, H2);
        int total = N * H3;
        self_init_kernel<5><<<EW_BLOCKS, 256, 0, stream>>>(buf0, dinv, out, total);
        scatter_kernel<5><<<SC_BLOCKS, 256, 0, stream>>>(buf0, srcp, dstp, dinv, out, E);
        bias_relu_kernel<5><<<EW_BLOCKS, 256, 0, stream>>>(out, b3, out, total);  // in-place
    }
}

// Round 3
// 455.237 us; speedup vs baseline: 1.9240x; 1.9240x over previous
//
#include <hip/hip_runtime.h>
#include <hip/hip_bf16.h>
#include <math.h>

// ---------------- small utility kernels ----------------

__global__ void zero_int_kernel(int* p, int n) {
    int i = blockIdx.x * blockDim.x + threadIdx.x;
    if (i < n) p[i] = 0;
}

__global__ void count_deg_kernel(const int* __restrict__ dst, int* deg, int E) {
    int i = blockIdx.x * blockDim.x + threadIdx.x;
    if (i < E) atomicAdd(&deg[dst[i]], 1);
}

__global__ void dinv_kernel(const int* __restrict__ deg, float* dinv, int n) {
    int i = blockIdx.x * blockDim.x + threadIdx.x;
    if (i < n) dinv[i] = rsqrtf((float)deg[i] + 1.0f);
}

// ---------------- exclusive scan of deg -> row_ptr (512 elems/block) ----------------

__global__ __launch_bounds__(256) void scan1_kernel(const int* __restrict__ deg,
                                                    int* __restrict__ row_ptr,
                                                    int* __restrict__ blockSums, int n) {
    __shared__ int sm[256];
    int t = threadIdx.x;
    int i = blockIdx.x * 512 + 2 * t;
    int v0 = 0, v1 = 0;
    if (i < n) { v0 = deg[i]; v1 = deg[i + 1]; }  // n even
    int ts = v0 + v1;
    sm[t] = ts;
    __syncthreads();
    for (int off = 1; off < 256; off <<= 1) {
        int u = (t >= off) ? sm[t - off] : 0;
        __syncthreads();
        sm[t] += u;
        __syncthreads();
    }
    int excl = sm[t] - ts;
    if (i < n) { row_ptr[i] = excl; row_ptr[i + 1] = excl + v0; }
    if (t == 255) blockSums[blockIdx.x] = sm[255];
}

__global__ __launch_bounds__(256) void scan2_kernel(const int* __restrict__ blockSums,
                                                    int* __restrict__ blockOffs, int nb) {
    __shared__ int sm[256];
    int t = threadIdx.x;
    int v = (t < nb) ? blockSums[t] : 0;
    sm[t] = v;
    __syncthreads();
    for (int off = 1; off < 256; off <<= 1) {
        int u = (t >= off) ? sm[t - off] : 0;
        __syncthreads();
        sm[t] += u;
        __syncthreads();
    }
    blockOffs[t] = sm[t] - v;
}

__global__ __launch_bounds__(256) void scan3_kernel(int* __restrict__ row_ptr,
                                                    int* __restrict__ cursor,
                                                    const int* __restrict__ blockOffs, int n) {
    int t = threadIdx.x;
    int i = blockIdx.x * 512 + 2 * t;
    int off = blockOffs[blockIdx.x];
    if (i < n) {
        int a = row_ptr[i] + off;
        int b = row_ptr[i + 1] + off;
        row_ptr[i] = a; cursor[i] = a;
        row_ptr[i + 1] = b; cursor[i + 1] = b;
    }
}

// ---------------- CSR fill: pack (src, coef) per edge, grouped by dst ----------------

__global__ void fill_kernel(const int* __restrict__ src, const int* __restrict__ dst,
                            const float* __restrict__ dinv, int* __restrict__ cursor,
                            int2* __restrict__ pack, int E) {
    int e = blockIdx.x * blockDim.x + threadIdx.x;
    if (e < E) {
        int s = src[e], d = dst[e];
        int pos = atomicAdd(&cursor[d], 1);
        pack[pos] = make_int2(s, __float_as_int(dinv[s] * dinv[d]));
    }
}

// ---------------- fp32 tiled GEMM: C[M,N] = A[M,K] @ B[K,N] ----------------

__global__ __launch_bounds__(256) void sgemm_kernel(const float* __restrict__ A,
                                                    const float* __restrict__ B,
                                                    float* __restrict__ C,
                                                    int M, int N, int K) {
    const int BM = 64, BN = 64, BK = 16;
    __shared__ float As[BK][BM + 1];
    __shared__ float Bs[BK][BN];

    int tid = threadIdx.x;
    int tx = tid & 15;
    int ty = tid >> 4;
    int bm0 = blockIdx.x * BM;
    int bn0 = blockIdx.y * BN;

    int arow = tid >> 2;
    int ak   = (tid & 3) * 4;
    int brow = tid >> 4;
    int bcol = (tid & 15) * 4;

    float acc[4][4] = {};

    for (int k0 = 0; k0 < K; k0 += BK) {
        int grow = bm0 + arow;
        if (grow < M) {
            const float4 v = *reinterpret_cast<const float4*>(A + (size_t)grow * K + k0 + ak);
            As[ak + 0][arow] = v.x;
            As[ak + 1][arow] = v.y;
            As[ak + 2][arow] = v.z;
            As[ak + 3][arow] = v.w;
        } else {
            As[ak + 0][arow] = 0.0f; As[ak + 1][arow] = 0.0f;
            As[ak + 2][arow] = 0.0f; As[ak + 3][arow] = 0.0f;
        }
        {
            const float* bp = B + (size_t)(k0 + brow) * N + bn0 + bcol;
#pragma unroll
            for (int j = 0; j < 4; ++j)
                Bs[brow][bcol + j] = (bn0 + bcol + j < N) ? bp[j] : 0.0f;
        }
        __syncthreads();

#pragma unroll
        for (int k = 0; k < BK; ++k) {
            float a[4], b[4];
#pragma unroll
            for (int i = 0; i < 4; ++i) a[i] = As[k][ty * 4 + i];
#pragma unroll
            for (int j = 0; j < 4; ++j) b[j] = Bs[k][tx * 4 + j];
#pragma unroll
            for (int i = 0; i < 4; ++i)
#pragma unroll
                for (int j = 0; j < 4; ++j) acc[i][j] += a[i] * b[j];
        }
        __syncthreads();
    }

#pragma unroll
    for (int i = 0; i < 4; ++i) {
        int r = bm0 + ty * 4 + i;
        if (r >= M) continue;
#pragma unroll
        for (int j = 0; j < 4; ++j) {
            int c = bn0 + tx * 4 + j;
            if (c < N) C[(size_t)r * N + c] = acc[i][j];
        }
    }
}

// ---------------- fused gather: out = relu(sum_in(coef*xw[src]) + dinv^2*xw[n] + b) ----------------
// one wave per destination node

template <int F>
__global__ __launch_bounds__(256) void gather_kernel(const float* __restrict__ xw,
                                                     const int* __restrict__ row_ptr,
                                                     const int* __restrict__ deg,
                                                     const int2* __restrict__ pack,
                                                     const float* __restrict__ dinv,
                                                     const float* __restrict__ bias,
                                                     float* __restrict__ out, int N) {
    int wid = blockIdx.x * 4 + (threadIdx.x >> 6);
    if (wid >= N) return;
    int lane = threadIdx.x & 63;
    constexpr int VPL = (F == 128) ? 2 : 1;
    const bool active = (F >= 64) || (lane < F);
    const int f0 = lane * VPL;

    float dn = dinv[wid];
    float acc0 = 0.0f, acc1 = 0.0f;
    const float* row = xw + (size_t)wid * F;
    if (active) {
        if constexpr (VPL == 2) {
            float2 v = *reinterpret_cast<const float2*>(row + f0);
            acc0 = v.x * dn * dn; acc1 = v.y * dn * dn;
        } else {
            acc0 = row[f0] * dn * dn;
        }
    }

    int beg = row_ptr[wid];
    int cnt = deg[wid];
    int j = 0;
    for (; j + 1 < cnt; j += 2) {
        int2 p0 = pack[beg + j];
        int2 p1 = pack[beg + j + 1];
        const float* r0 = xw + (size_t)p0.x * F;
        const float* r1 = xw + (size_t)p1.x * F;
        float c0 = __int_as_float(p0.y);
        float c1 = __int_as_float(p1.y);
        if (active) {
            if constexpr (VPL == 2) {
                float2 v0 = *reinterpret_cast<const float2*>(r0 + f0);
                float2 v1 = *reinterpret_cast<const float2*>(r1 + f0);
                acc0 += v0.x * c0 + v1.x * c1;
                acc1 += v0.y * c0 + v1.y * c1;
            } else {
                acc0 += r0[f0] * c0 + r1[f0] * c1;
            }
        }
    }
    if (j < cnt) {
        int2 p0 = pack[beg + j];
        const float* r0 = xw + (size_t)p0.x * F;
        float c0 = __int_as_float(p0.y);
        if (active) {
            if constexpr (VPL == 2) {
                float2 v0 = *reinterpret_cast<const float2*>(r0 + f0);
                acc0 += v0.x * c0; acc1 += v0.y * c0;
            } else {
                acc0 += r0[f0] * c0;
            }
        }
    }

    if (active) {
        if constexpr (VPL == 2) {
            float2 bv = *reinterpret_cast<const float2*>(bias + f0);
            float2 o;
            o.x = fmaxf(acc0 + bv.x, 0.0f);
            o.y = fmaxf(acc1 + bv.y, 0.0f);
            *reinterpret_cast<float2*>(out + (size_t)wid * F + f0) = o;
        } else {
            out[(size_t)wid * F + f0] = fmaxf(acc0 + bias[f0], 0.0f);
        }
    }
}

// ---------------- launch ----------------

extern "C" void kernel_launch(void* const* d_in, const int* in_sizes, int n_in,
                              void* d_out, int out_size, void* d_ws, size_t ws_size,
                              hipStream_t stream) {
    const float* x = (const float*)d_in[0];
    const int* edge = (const int*)d_in[1];
    const float* W1 = (const float*)d_in[2];
    const float* b1 = (const float*)d_in[3];
    const float* W2 = (const float*)d_in[4];
    const float* b2 = (const float*)d_in[5];
    const float* W3 = (const float*)d_in[6];
    const float* b3 = (const float*)d_in[7];

    const int C_IN = 256, H1 = 128, H2 = 64, H3 = 32;
    const int N = in_sizes[0] / C_IN;   // 100000
    const int E = in_sizes[1] / 2;      // 800000
    const int* srcp = edge;
    const int* dstp = edge + E;

    // ---- workspace carve ----
    char* p = (char*)d_ws;
    size_t o = 0;
    auto alloc = [&](size_t bytes) -> void* {
        void* r = p + o;
        o = (o + bytes + 255) & ~(size_t)255;
        return r;
    };
    float* dinv     = (float*)alloc((size_t)N * 4);
    int*   deg      = (int*)alloc((size_t)N * 4);
    int*   row_ptr  = (int*)alloc((size_t)N * 4);
    int*   cursor   = (int*)alloc((size_t)N * 4);
    int*   blockSums= (int*)alloc(1024);
    int*   blockOffs= (int*)alloc(1024);
    int2*  pack     = (int2*)alloc((size_t)E * 8);
    float* buf0     = (float*)alloc((size_t)N * H1 * 4);
    float* buf1     = (float*)alloc((size_t)N * H1 * 4);
    float* out      = (float*)d_out;

    const int NB = (N + 511) / 512;  // 196 <= 256

    // ---- CSR build (once per call) ----
    zero_int_kernel<<<(N + 255) / 256, 256, 0, stream>>>(deg, N);
    count_deg_kernel<<<(E + 255) / 256, 256, 0, stream>>>(dstp, deg, E);
    dinv_kernel<<<(N + 255) / 256, 256, 0, stream>>>(deg, dinv, N);
    scan1_kernel<<<NB, 256, 0, stream>>>(deg, row_ptr, blockSums, N);
    scan2_kernel<<<1, 256, 0, stream>>>(blockSums, blockOffs, NB);
    scan3_kernel<<<NB, 256, 0, stream>>>(row_ptr, cursor, blockOffs, N);
    fill_kernel<<<(E + 255) / 256, 256, 0, stream>>>(srcp, dstp, dinv, cursor, pack, E);

    const int GATHER_BLOCKS = (N + 3) / 4;

    // ---- layer 1: 256 -> 128 ----
    {
        dim3 grid((N + 63) / 64, (H1 + 63) / 64);
        sgemm_kernel<<<grid, 256, 0, stream>>>(x, W1, buf0, N, H1, C_IN);
        gather_kernel<128><<<GATHER_BLOCKS, 256, 0, stream>>>(buf0, row_ptr, deg, pack, dinv, b1, buf1, N);
    }
    // ---- layer 2: 128 -> 64 ----
    {
        dim3 grid((N + 63) / 64, (H2 + 63) / 64);
        sgemm_kernel<<<grid, 256, 0, stream>>>(buf1, W2, buf0, N, H2, H1);
        gather_kernel<64><<<GATHER_BLOCKS, 256, 0, stream>>>(buf0, row_ptr, deg, pack, dinv, b2, buf1, N);
    }
    // ---- layer 3: 64 -> 32 ----
    {
        dim3 grid((N + 63) / 64, (H3 + 63) / 64);
        sgemm_kernel<<<grid, 256, 0, stream>>>(buf1, W3, buf0, N, H3, H2);
        gather_kernel<32><<<GATHER_BLOCKS, 256, 0, stream>>>(buf0, row_ptr, deg, pack, dinv, b3, out, N);
    }
}

// Round 4
// 331.638 us; speedup vs baseline: 2.6410x; 1.3727x over previous
//
#include <hip/hip_runtime.h>
#include <hip/hip_bf16.h>
#include <math.h>

typedef __attribute__((ext_vector_type(8))) short s16x8;
typedef __attribute__((ext_vector_type(4))) float f32x4;

// ---------------- small utility kernels ----------------

__global__ void zero_int_kernel(int* p, int n) {
    int i = blockIdx.x * blockDim.x + threadIdx.x;
    if (i < n) p[i] = 0;
}

__global__ void count_deg_kernel(const int* __restrict__ dst, int* deg, int E) {
    int i = blockIdx.x * blockDim.x + threadIdx.x;
    if (i < E) atomicAdd(&deg[dst[i]], 1);
}

__global__ void dinv_kernel(const int* __restrict__ deg, float* dinv, int n) {
    int i = blockIdx.x * blockDim.x + threadIdx.x;
    if (i < n) dinv[i] = rsqrtf((float)deg[i] + 1.0f);
}

__device__ __forceinline__ unsigned short f2bf(float f) {
    unsigned int u = __float_as_uint(f);
    u += 0x7fffu + ((u >> 16) & 1u);
    return (unsigned short)(u >> 16);
}

// W[K][N] fp32 -> Wt[N][K+8] bf16 bits (padded rows to de-conflict LDS banks)
__global__ void conv_w_kernel(const float* __restrict__ W, unsigned short* __restrict__ Wt,
                              int K, int N) {
    int i = blockIdx.x * blockDim.x + threadIdx.x;
    if (i < K * N) {
        int k = i / N, n = i % N;
        Wt[(size_t)n * (K + 8) + k] = f2bf(W[i]);
    }
}

// ---------------- exclusive scan of deg -> row_ptr (512 elems/block) ----------------

__global__ __launch_bounds__(256) void scan1_kernel(const int* __restrict__ deg,
                                                    int* __restrict__ row_ptr,
                                                    int* __restrict__ blockSums, int n) {
    __shared__ int sm[256];
    int t = threadIdx.x;
    int i = blockIdx.x * 512 + 2 * t;
    int v0 = 0, v1 = 0;
    if (i < n) { v0 = deg[i]; v1 = deg[i + 1]; }  // n even
    int ts = v0 + v1;
    sm[t] = ts;
    __syncthreads();
    for (int off = 1; off < 256; off <<= 1) {
        int u = (t >= off) ? sm[t - off] : 0;
        __syncthreads();
        sm[t] += u;
        __syncthreads();
    }
    int excl = sm[t] - ts;
    if (i < n) { row_ptr[i] = excl; row_ptr[i + 1] = excl + v0; }
    if (t == 255) blockSums[blockIdx.x] = sm[255];
}

__global__ __launch_bounds__(256) void scan2_kernel(const int* __restrict__ blockSums,
                                                    int* __restrict__ blockOffs, int nb) {
    __shared__ int sm[256];
    int t = threadIdx.x;
    int v = (t < nb) ? blockSums[t] : 0;
    sm[t] = v;
    __syncthreads();
    for (int off = 1; off < 256; off <<= 1) {
        int u = (t >= off) ? sm[t - off] : 0;
        __syncthreads();
        sm[t] += u;
        __syncthreads();
    }
    blockOffs[t] = sm[t] - v;
}

__global__ __launch_bounds__(256) void scan3_kernel(int* __restrict__ row_ptr,
                                                    int* __restrict__ cursor,
                                                    const int* __restrict__ blockOffs, int n) {
    int t = threadIdx.x;
    int i = blockIdx.x * 512 + 2 * t;
    int off = blockOffs[blockIdx.x];
    if (i < n) {
        int a = row_ptr[i] + off;
        int b = row_ptr[i + 1] + off;
        row_ptr[i] = a; cursor[i] = a;
        row_ptr[i + 1] = b; cursor[i + 1] = b;
    }
}

// ---------------- CSR fill: pack (src, coef) per edge, grouped by dst ----------------

__global__ void fill_kernel(const int* __restrict__ src, const int* __restrict__ dst,
                            const float* __restrict__ dinv, int* __restrict__ cursor,
                            int2* __restrict__ pack, int E) {
    int e = blockIdx.x * blockDim.x + threadIdx.x;
    if (e < E) {
        int s = src[e], d = dst[e];
        int pos = atomicAdd(&cursor[d], 1);
        pack[pos] = make_int2(s, __float_as_int(dinv[s] * dinv[d]));
    }
}

// ---------------- bf16 MFMA GEMM: C_bf16[M,N] = A_f32[M,K] @ Wt_bf16 ----------------
// Wt is [N][K+8] bf16 (pre-transposed, padded). Whole Wt staged in LDS.
// Block = 256 threads = 4 waves; each wave owns 32 rows; BM = 128.
// A fragments loaded fp32 from global, converted in-register (packed cvt).

__device__ __forceinline__ s16x8 cvt8(const float4& u, const float4& v) {
    union { unsigned int w[4]; s16x8 s; } cb;
    __hip_bfloat162 h;
    h = __float22bfloat162_rn(make_float2(u.x, u.y)); cb.w[0] = *(unsigned int*)&h;
    h = __float22bfloat162_rn(make_float2(u.z, u.w)); cb.w[1] = *(unsigned int*)&h;
    h = __float22bfloat162_rn(make_float2(v.x, v.y)); cb.w[2] = *(unsigned int*)&h;
    h = __float22bfloat162_rn(make_float2(v.z, v.w)); cb.w[3] = *(unsigned int*)&h;
    return cb.s;
}

template <int K, int N>
__global__ __launch_bounds__(256) void mfma_gemm_kernel(const float* __restrict__ A,
                                                        const unsigned short* __restrict__ Bt,
                                                        __hip_bfloat16* __restrict__ C, int M) {
    constexpr int KP = K + 8;
    constexpr int KSTEPS = K / 32;
    constexpr int NFRAG = N / 16;
    constexpr int BYTES = N * KP * 2;
    __shared__ unsigned short Blds[N * KP];

    int tid = threadIdx.x;
    for (int off = tid * 16; off < BYTES; off += 256 * 16) {
        *(float4*)((char*)Blds + off) = *(const float4*)((const char*)Bt + off);
    }
    __syncthreads();

    int wv = tid >> 6, lane = tid & 63;
    int r0 = blockIdx.x * 128 + wv * 32;
    int lr = lane & 15, kg = lane >> 4;
    const float* a0p = A + (size_t)min(r0 + lr, M - 1) * K + kg * 8;
    const float* a1p = A + (size_t)min(r0 + 16 + lr, M - 1) * K + kg * 8;

    f32x4 acc[2][NFRAG] = {};

#pragma unroll
    for (int ks = 0; ks < KSTEPS; ++ks) {
        s16x8 a0, a1;
        {
            const float* p = a0p + ks * 32;
            float4 u = *(const float4*)p;
            float4 v = *(const float4*)(p + 4);
            a0 = cvt8(u, v);
            p = a1p + ks * 32;
            u = *(const float4*)p;
            v = *(const float4*)(p + 4);
            a1 = cvt8(u, v);
        }
#pragma unroll
        for (int ni = 0; ni < NFRAG; ++ni) {
            const s16x8 b = *(const s16x8*)&Blds[(ni * 16 + lr) * KP + kg * 8 + ks * 32];
            acc[0][ni] = __builtin_amdgcn_mfma_f32_16x16x32_bf16(a0, b, acc[0][ni], 0, 0, 0);
            acc[1][ni] = __builtin_amdgcn_mfma_f32_16x16x32_bf16(a1, b, acc[1][ni], 0, 0, 0);
        }
    }

    // C/D layout: col = lane&15, row = (lane>>4)*4 + reg  (m89-verified)
    int rb = kg * 4;
#pragma unroll
    for (int mi = 0; mi < 2; ++mi) {
#pragma unroll
        for (int r = 0; r < 4; ++r) {
            int row = r0 + mi * 16 + rb + r;
            if (row < M) {
#pragma unroll
                for (int ni = 0; ni < NFRAG; ++ni) {
                    C[(size_t)row * N + ni * 16 + lr] = __float2bfloat16(acc[mi][ni][r]);
                }
            }
        }
    }
}

// ---------------- fused gather: out = relu(sum_in(coef*xw[src]) + dinv^2*xw[n] + b) ----------------
// one wave per destination node; xw is bf16, accumulate fp32, output fp32

template <int F>
__global__ __launch_bounds__(256) void gather_kernel(const unsigned short* __restrict__ xw,
                                                     const int* __restrict__ row_ptr,
                                                     const int* __restrict__ deg,
                                                     const int2* __restrict__ pack,
                                                     const float* __restrict__ dinv,
                                                     const float* __restrict__ bias,
                                                     float* __restrict__ out, int N) {
    int wid = blockIdx.x * 4 + (threadIdx.x >> 6);
    if (wid >= N) return;
    int lane = threadIdx.x & 63;
    constexpr int VPL = (F == 128) ? 2 : 1;
    const bool active = (F >= 64) || (lane < F);
    const int f0 = lane * VPL;

    float dn = dinv[wid];
    float acc0 = 0.0f, acc1 = 0.0f;
    const unsigned short* row = xw + (size_t)wid * F;
    if (active) {
        if constexpr (VPL == 2) {
            unsigned int b = *(const unsigned int*)(row + f0);
            acc0 = __uint_as_float(b << 16) * dn * dn;
            acc1 = __uint_as_float(b & 0xffff0000u) * dn * dn;
        } else {
            acc0 = __uint_as_float((unsigned int)row[f0] << 16) * dn * dn;
        }
    }

    int beg = row_ptr[wid];
    int cnt = deg[wid];
    int j = 0;
    for (; j + 1 < cnt; j += 2) {
        int2 p0 = pack[beg + j];
        int2 p1 = pack[beg + j + 1];
        const unsigned short* r0 = xw + (size_t)p0.x * F;
        const unsigned short* r1 = xw + (size_t)p1.x * F;
        float c0 = __int_as_float(p0.y);
        float c1 = __int_as_float(p1.y);
        if (active) {
            if constexpr (VPL == 2) {
                unsigned int b0 = *(const unsigned int*)(r0 + f0);
                unsigned int b1 = *(const unsigned int*)(r1 + f0);
                acc0 += __uint_as_float(b0 << 16) * c0 + __uint_as_float(b1 << 16) * c1;
                acc1 += __uint_as_float(b0 & 0xffff0000u) * c0 +
                        __uint_as_float(b1 & 0xffff0000u) * c1;
            } else {
                acc0 += __uint_as_float((unsigned int)r0[f0] << 16) * c0 +
                        __uint_as_float((unsigned int)r1[f0] << 16) * c1;
            }
        }
    }
    if (j < cnt) {
        int2 p0 = pack[beg + j];
        const unsigned short* r0 = xw + (size_t)p0.x * F;
        float c0 = __int_as_float(p0.y);
        if (active) {
            if constexpr (VPL == 2) {
                unsigned int b0 = *(const unsigned int*)(r0 + f0);
                acc0 += __uint_as_float(b0 << 16) * c0;
                acc1 += __uint_as_float(b0 & 0xffff0000u) * c0;
            } else {
                acc0 += __uint_as_float((unsigned int)r0[f0] << 16) * c0;
            }
        }
    }

    if (active) {
        if constexpr (VPL == 2) {
            float2 o;
            o.x = fmaxf(acc0 + bias[f0], 0.0f);
            o.y = fmaxf(acc1 + bias[f0 + 1], 0.0f);
            *reinterpret_cast<float2*>(out + (size_t)wid * F + f0) = o;
        } else {
            out[(size_t)wid * F + f0] = fmaxf(acc0 + bias[f0], 0.0f);
        }
    }
}

// ---------------- launch ----------------

extern "C" void kernel_launch(void* const* d_in, const int* in_sizes, int n_in,
                              void* d_out, int out_size, void* d_ws, size_t ws_size,
                              hipStream_t stream) {
    const float* x = (const float*)d_in[0];
    const int* edge = (const int*)d_in[1];
    const float* W1 = (const float*)d_in[2];
    const float* b1 = (const float*)d_in[3];
    const float* W2 = (const float*)d_in[4];
    const float* b2 = (const float*)d_in[5];
    const float* W3 = (const float*)d_in[6];
    const float* b3 = (const float*)d_in[7];

    const int C_IN = 256, H1 = 128, H2 = 64, H3 = 32;
    const int N = in_sizes[0] / C_IN;   // 100000
    const int E = in_sizes[1] / 2;      // 800000
    const int* srcp = edge;
    const int* dstp = edge + E;

    // ---- workspace carve ----
    char* p = (char*)d_ws;
    size_t o = 0;
    auto alloc = [&](size_t bytes) -> void* {
        void* r = p + o;
        o = (o + bytes + 255) & ~(size_t)255;
        return r;
    };
    float* dinv      = (float*)alloc((size_t)N * 4);
    int*   deg       = (int*)alloc((size_t)N * 4);
    int*   row_ptr   = (int*)alloc((size_t)N * 4);
    int*   cursor    = (int*)alloc((size_t)N * 4);
    int*   blockSums = (int*)alloc(1024);
    int*   blockOffs = (int*)alloc(1024);
    int2*  pack      = (int2*)alloc((size_t)E * 8);
    unsigned short* Wt1 = (unsigned short*)alloc((size_t)H1 * (C_IN + 8) * 2);
    unsigned short* Wt2 = (unsigned short*)alloc((size_t)H2 * (H1 + 8) * 2);
    unsigned short* Wt3 = (unsigned short*)alloc((size_t)H3 * (H2 + 8) * 2);
    unsigned short* xwb = (unsigned short*)alloc((size_t)N * H1 * 2);  // bf16 xw (max 25.6 MB)
    float* actb = (float*)alloc((size_t)N * H1 * 4);                   // fp32 activations
    float* out = (float*)d_out;

    const int NB = (N + 511) / 512;  // 196 <= 256

    // ---- CSR build + weight transpose/convert (once per call) ----
    zero_int_kernel<<<(N + 255) / 256, 256, 0, stream>>>(deg, N);
    count_deg_kernel<<<(E + 255) / 256, 256, 0, stream>>>(dstp, deg, E);
    dinv_kernel<<<(N + 255) / 256, 256, 0, stream>>>(deg, dinv, N);
    scan1_kernel<<<NB, 256, 0, stream>>>(deg, row_ptr, blockSums, N);
    scan2_kernel<<<1, 256, 0, stream>>>(blockSums, blockOffs, NB);
    scan3_kernel<<<NB, 256, 0, stream>>>(row_ptr, cursor, blockOffs, N);
    fill_kernel<<<(E + 255) / 256, 256, 0, stream>>>(srcp, dstp, dinv, cursor, pack, E);
    conv_w_kernel<<<(C_IN * H1 + 255) / 256, 256, 0, stream>>>(W1, Wt1, C_IN, H1);
    conv_w_kernel<<<(H1 * H2 + 255) / 256, 256, 0, stream>>>(W2, Wt2, H1, H2);
    conv_w_kernel<<<(H2 * H3 + 255) / 256, 256, 0, stream>>>(W3, Wt3, H2, H3);

    const int GEMM_BLOCKS = (N + 127) / 128;
    const int GATHER_BLOCKS = (N + 3) / 4;

    // ---- layer 1: 256 -> 128 ----
    mfma_gemm_kernel<256, 128><<<GEMM_BLOCKS, 256, 0, stream>>>(x, Wt1, (__hip_bfloat16*)xwb, N);
    gather_kernel<128><<<GATHER_BLOCKS, 256, 0, stream>>>(xwb, row_ptr, deg, pack, dinv, b1, actb, N);
    // ---- layer 2: 128 -> 64 ----
    mfma_gemm_kernel<128, 64><<<GEMM_BLOCKS, 256, 0, stream>>>(actb, Wt2, (__hip_bfloat16*)xwb, N);
    gather_kernel<64><<<GATHER_BLOCKS, 256, 0, stream>>>(xwb, row_ptr, deg, pack, dinv, b2, actb, N);
    // ---- layer 3: 64 -> 32 ----
    mfma_gemm_kernel<64, 32><<<GEMM_BLOCKS, 256, 0, stream>>>(actb, Wt3, (__hip_bfloat16*)xwb, N);
    gather_kernel<32><<<GATHER_BLOCKS, 256, 0, stream>>>(xwb, row_ptr, deg, pack, dinv, b3, out, N);
}

// Round 5
// 262.545 us; speedup vs baseline: 3.3361x; 1.2632x over previous
//
#include <hip/hip_runtime.h>
#include <hip/hip_bf16.h>
#include <math.h>

typedef __attribute__((ext_vector_type(8))) short s16x8;
typedef __attribute__((ext_vector_type(4))) float f32x4;

__device__ __forceinline__ unsigned short f2bf(float f) {
    unsigned int u = __float_as_uint(f);
    u += 0x7fffu + ((u >> 16) & 1u);
    return (unsigned short)(u >> 16);
}

// ---------------- small utility kernels ----------------

__global__ void zero_int_kernel(int* p, int n) {
    int i = blockIdx.x * blockDim.x + threadIdx.x;
    if (i < n) p[i] = 0;
}

__global__ void count_deg_kernel(const int* __restrict__ dst, int* deg, int E) {
    int i = blockIdx.x * blockDim.x + threadIdx.x;
    if (i < E) atomicAdd(&deg[dst[i]], 1);
}

// all three weights: W[K][N] fp32 -> Wt[N][K+8] bf16
__global__ void conv_w3_kernel(const float* __restrict__ W1, const float* __restrict__ W2,
                               const float* __restrict__ W3, unsigned short* __restrict__ Wt1,
                               unsigned short* __restrict__ Wt2, unsigned short* __restrict__ Wt3) {
    int i = blockIdx.x * blockDim.x + threadIdx.x;
    if (i < 32768) {                       // 256x128
        int k = i >> 7, n = i & 127;
        Wt1[(size_t)n * 264 + k] = f2bf(W1[i]);
    } else if (i < 40960) {                // 128x64
        int j = i - 32768, k = j >> 6, n = j & 63;
        Wt2[(size_t)n * 136 + k] = f2bf(W2[j]);
    } else if (i < 43008) {                // 64x32
        int j = i - 40960, k = j >> 5, n = j & 31;
        Wt3[(size_t)n * 72 + k] = f2bf(W3[j]);
    }
}

// ---------------- exclusive scan of deg -> row_ptr (+ dinv) ----------------

__global__ __launch_bounds__(256) void scan1_kernel(const int* __restrict__ deg,
                                                    int* __restrict__ row_ptr,
                                                    int* __restrict__ blockSums,
                                                    float* __restrict__ dinv, int n) {
    __shared__ int sm[256];
    int t = threadIdx.x;
    int i = blockIdx.x * 512 + 2 * t;
    int v0 = 0, v1 = 0;
    if (i < n) { v0 = deg[i]; v1 = deg[i + 1]; }  // n even
    if (i < n) {
        dinv[i] = rsqrtf((float)v0 + 1.0f);
        dinv[i + 1] = rsqrtf((float)v1 + 1.0f);
    }
    int ts = v0 + v1;
    sm[t] = ts;
    __syncthreads();
    for (int off = 1; off < 256; off <<= 1) {
        int u = (t >= off) ? sm[t - off] : 0;
        __syncthreads();
        sm[t] += u;
        __syncthreads();
    }
    int excl = sm[t] - ts;
    if (i < n) { row_ptr[i] = excl; row_ptr[i + 1] = excl + v0; }
    if (t == 255) blockSums[blockIdx.x] = sm[255];
}

__global__ __launch_bounds__(256) void scan2_kernel(const int* __restrict__ blockSums,
                                                    int* __restrict__ blockOffs, int nb) {
    __shared__ int sm[256];
    int t = threadIdx.x;
    int v = (t < nb) ? blockSums[t] : 0;
    sm[t] = v;
    __syncthreads();
    for (int off = 1; off < 256; off <<= 1) {
        int u = (t >= off) ? sm[t - off] : 0;
        __syncthreads();
        sm[t] += u;
        __syncthreads();
    }
    blockOffs[t] = sm[t] - v;
}

__global__ __launch_bounds__(256) void scan3_kernel(int* __restrict__ row_ptr,
                                                    int* __restrict__ cursor,
                                                    const int* __restrict__ blockOffs, int n) {
    int t = threadIdx.x;
    int i = blockIdx.x * 512 + 2 * t;
    int off = blockOffs[blockIdx.x];
    if (i < n) {
        int a = row_ptr[i] + off;
        int b = row_ptr[i + 1] + off;
        row_ptr[i] = a; cursor[i] = a;
        row_ptr[i + 1] = b; cursor[i + 1] = b;
    }
}

// ---------------- CSR fill: pack (src, coef) per edge, grouped by dst ----------------

__global__ void fill_kernel(const int* __restrict__ src, const int* __restrict__ dst,
                            const float* __restrict__ dinv, int* __restrict__ cursor,
                            int2* __restrict__ pack, int E) {
    int e = blockIdx.x * blockDim.x + threadIdx.x;
    if (e < E) {
        int s = src[e], d = dst[e];
        int pos = atomicAdd(&cursor[d], 1);
        pack[pos] = make_int2(s, __float_as_int(dinv[s] * dinv[d]));
    }
}

// ---------------- bf16 MFMA GEMM: C_bf16[M,N] = A[M,K] @ Wt_bf16 ----------------
// Wt pre-transposed [N][K+8] bf16, whole W staged in LDS once (no K-loop barrier).
// 512 threads = 8 waves, BM = 256 rows (32/wave). A is fp32 (cvt in-register) or bf16.

__device__ __forceinline__ s16x8 cvt8(const float4& u, const float4& v) {
    union { unsigned int w[4]; s16x8 s; } cb;
    __hip_bfloat162 h;
    h = __float22bfloat162_rn(make_float2(u.x, u.y)); cb.w[0] = *(unsigned int*)&h;
    h = __float22bfloat162_rn(make_float2(u.z, u.w)); cb.w[1] = *(unsigned int*)&h;
    h = __float22bfloat162_rn(make_float2(v.x, v.y)); cb.w[2] = *(unsigned int*)&h;
    h = __float22bfloat162_rn(make_float2(v.z, v.w)); cb.w[3] = *(unsigned int*)&h;
    return cb.s;
}

template <int K, int N, bool ABF16>
__global__ __launch_bounds__(512) void mfma_gemm_kernel(const void* __restrict__ Av,
                                                        const unsigned short* __restrict__ Bt,
                                                        unsigned short* __restrict__ C, int M) {
    constexpr int KP = K + 8;
    constexpr int KSTEPS = K / 32;
    constexpr int NFRAG = N / 16;
    constexpr int BYTES = N * KP * 2;
    __shared__ unsigned short Blds[N * KP];

    int tid = threadIdx.x;
    for (int off = tid * 16; off < BYTES; off += 512 * 16)
        *(float4*)((char*)Blds + off) = *(const float4*)((const char*)Bt + off);
    __syncthreads();

    int wv = tid >> 6, lane = tid & 63;
    int r0 = blockIdx.x * 256 + wv * 32;
    int lr = lane & 15, kg = lane >> 4;
    int ra = min(r0 + lr, M - 1);
    int rb = min(r0 + 16 + lr, M - 1);

    f32x4 acc[2][NFRAG] = {};

    const float* a0f = nullptr; const float* a1f = nullptr;
    const unsigned short* a0h = nullptr; const unsigned short* a1h = nullptr;
    if constexpr (ABF16) {
        a0h = (const unsigned short*)Av + (size_t)ra * K + kg * 8;
        a1h = (const unsigned short*)Av + (size_t)rb * K + kg * 8;
    } else {
        a0f = (const float*)Av + (size_t)ra * K + kg * 8;
        a1f = (const float*)Av + (size_t)rb * K + kg * 8;
    }

#pragma unroll
    for (int ks = 0; ks < KSTEPS; ++ks) {
        s16x8 a0, a1;
        if constexpr (ABF16) {
            a0 = *(const s16x8*)(a0h + ks * 32);
            a1 = *(const s16x8*)(a1h + ks * 32);
        } else {
            float4 u = *(const float4*)(a0f + ks * 32);
            float4 v = *(const float4*)(a0f + ks * 32 + 4);
            a0 = cvt8(u, v);
            u = *(const float4*)(a1f + ks * 32);
            v = *(const float4*)(a1f + ks * 32 + 4);
            a1 = cvt8(u, v);
        }
#pragma unroll
        for (int ni = 0; ni < NFRAG; ++ni) {
            const s16x8 b = *(const s16x8*)&Blds[(ni * 16 + lr) * KP + kg * 8 + ks * 32];
            acc[0][ni] = __builtin_amdgcn_mfma_f32_16x16x32_bf16(a0, b, acc[0][ni], 0, 0, 0);
            acc[1][ni] = __builtin_amdgcn_mfma_f32_16x16x32_bf16(a1, b, acc[1][ni], 0, 0, 0);
        }
    }

    // C/D layout: col = lane&15, row = (lane>>4)*4 + reg
    int rbase = kg * 4;
#pragma unroll
    for (int mi = 0; mi < 2; ++mi) {
#pragma unroll
        for (int r = 0; r < 4; ++r) {
            int row = r0 + mi * 16 + rbase + r;
            if (row < M) {
#pragma unroll
                for (int ni = 0; ni < NFRAG; ++ni)
                    C[(size_t)row * N + ni * 16 + lr] = f2bf(acc[mi][ni][r]);
            }
        }
    }
}

// ---------------- fused gather: out = relu(sum(coef*xw[src]) + dinv^2*xw[n] + b) ----------------
// GPW dst-groups per wave; xw bf16; fp32 accumulate; bf16 or fp32 output.

template <int F, int GPW, int VPL, bool OUT_BF16>
__global__ __launch_bounds__(256) void gather_kernel(const unsigned short* __restrict__ xw,
                                                     const int* __restrict__ row_ptr,
                                                     const int* __restrict__ deg,
                                                     const int2* __restrict__ pack,
                                                     const float* __restrict__ dinv,
                                                     const float* __restrict__ bias,
                                                     void* __restrict__ outv, int N) {
    int wave = blockIdx.x * 4 + (threadIdx.x >> 6);
    int lane = threadIdx.x & 63;
    int wid, gl;
    if constexpr (GPW == 2) {
        wid = wave * 2 + (lane >> 5);
        gl = lane & 31;
    } else {
        wid = wave;
        gl = lane;
    }
    if (wid >= N) return;
    const int f0 = gl * VPL;

    float x0, x1;
    auto loadrow = [&](const unsigned short* r, float& y0, float& y1) {
        if constexpr (VPL == 2) {
            unsigned int b = *(const unsigned int*)(r + f0);
            y0 = __uint_as_float(b << 16);
            y1 = __uint_as_float(b & 0xffff0000u);
        } else {
            y0 = __uint_as_float((unsigned int)r[f0] << 16);
            y1 = 0.0f;
        }
    };

    float dn = dinv[wid];
    loadrow(xw + (size_t)wid * F, x0, x1);
    float acc0 = x0 * dn * dn, acc1 = x1 * dn * dn;

    int beg = row_ptr[wid];
    int cnt = deg[wid];
    int j = 0;
    for (; j + 3 < cnt; j += 4) {
        int2 p0 = pack[beg + j];
        int2 p1 = pack[beg + j + 1];
        int2 p2 = pack[beg + j + 2];
        int2 p3 = pack[beg + j + 3];
        float u0, u1, v0, v1, w0, w1, z0, z1;
        loadrow(xw + (size_t)p0.x * F, u0, u1);
        loadrow(xw + (size_t)p1.x * F, v0, v1);
        loadrow(xw + (size_t)p2.x * F, w0, w1);
        loadrow(xw + (size_t)p3.x * F, z0, z1);
        float c0 = __int_as_float(p0.y), c1 = __int_as_float(p1.y);
        float c2 = __int_as_float(p2.y), c3 = __int_as_float(p3.y);
        acc0 += u0 * c0 + v0 * c1 + w0 * c2 + z0 * c3;
        acc1 += u1 * c0 + v1 * c1 + w1 * c2 + z1 * c3;
    }
    for (; j < cnt; ++j) {
        int2 p0 = pack[beg + j];
        float u0, u1;
        loadrow(xw + (size_t)p0.x * F, u0, u1);
        float c0 = __int_as_float(p0.y);
        acc0 += u0 * c0;
        acc1 += u1 * c0;
    }

    float o0 = fmaxf(acc0 + bias[f0], 0.0f);
    if constexpr (VPL == 2) {
        float o1 = fmaxf(acc1 + bias[f0 + 1], 0.0f);
        if constexpr (OUT_BF16) {
            __hip_bfloat162 h = __float22bfloat162_rn(make_float2(o0, o1));
            *(unsigned int*)((unsigned short*)outv + (size_t)wid * F + f0) = *(unsigned int*)&h;
        } else {
            *(float2*)((float*)outv + (size_t)wid * F + f0) = make_float2(o0, o1);
        }
    } else {
        if constexpr (OUT_BF16) {
            ((unsigned short*)outv)[(size_t)wid * F + f0] = f2bf(o0);
        } else {
            ((float*)outv)[(size_t)wid * F + f0] = o0;
        }
    }
}

// ---------------- launch ----------------

extern "C" void kernel_launch(void* const* d_in, const int* in_sizes, int n_in,
                              void* d_out, int out_size, void* d_ws, size_t ws_size,
                              hipStream_t stream) {
    const float* x = (const float*)d_in[0];
    const int* edge = (const int*)d_in[1];
    const float* W1 = (const float*)d_in[2];
    const float* b1 = (const float*)d_in[3];
    const float* W2 = (const float*)d_in[4];
    const float* b2 = (const float*)d_in[5];
    const float* W3 = (const float*)d_in[6];
    const float* b3 = (const float*)d_in[7];

    const int C_IN = 256, H1 = 128;
    const int N = in_sizes[0] / C_IN;   // 100000
    const int E = in_sizes[1] / 2;      // 800000
    const int* srcp = edge;
    const int* dstp = edge + E;

    // ---- workspace carve ----
    char* p = (char*)d_ws;
    size_t o = 0;
    auto alloc = [&](size_t bytes) -> void* {
        void* r = p + o;
        o = (o + bytes + 255) & ~(size_t)255;
        return r;
    };
    float* dinv      = (float*)alloc((size_t)N * 4);
    int*   deg       = (int*)alloc((size_t)N * 4);
    int*   row_ptr   = (int*)alloc((size_t)N * 4);
    int*   cursor    = (int*)alloc((size_t)N * 4);
    int*   blockSums = (int*)alloc(1024);
    int*   blockOffs = (int*)alloc(1024);
    int2*  pack      = (int2*)alloc((size_t)E * 8);
    unsigned short* Wt1 = (unsigned short*)alloc((size_t)128 * 264 * 2);
    unsigned short* Wt2 = (unsigned short*)alloc((size_t)64 * 136 * 2);
    unsigned short* Wt3 = (unsigned short*)alloc((size_t)32 * 72 * 2);
    unsigned short* xwb = (unsigned short*)alloc((size_t)N * H1 * 2);  // bf16 xw
    unsigned short* act = (unsigned short*)alloc((size_t)N * H1 * 2);  // bf16 activations
    float* out = (float*)d_out;

    const int NB = (N + 511) / 512;  // 196 <= 256

    // ---- CSR build + weight transpose/convert ----
    zero_int_kernel<<<(N + 255) / 256, 256, 0, stream>>>(cursor, N);  // reuse as zero buf target
    zero_int_kernel<<<(N + 255) / 256, 256, 0, stream>>>(deg, N);
    count_deg_kernel<<<(E + 255) / 256, 256, 0, stream>>>(dstp, deg, E);
    scan1_kernel<<<NB, 256, 0, stream>>>(deg, row_ptr, blockSums, dinv, N);
    scan2_kernel<<<1, 256, 0, stream>>>(blockSums, blockOffs, NB);
    scan3_kernel<<<NB, 256, 0, stream>>>(row_ptr, cursor, blockOffs, N);
    fill_kernel<<<(E + 255) / 256, 256, 0, stream>>>(srcp, dstp, dinv, cursor, pack, E);
    conv_w3_kernel<<<(43008 + 255) / 256, 256, 0, stream>>>(W1, W2, W3, Wt1, Wt2, Wt3);

    const int GEMM_BLOCKS = (N + 255) / 256;

    // ---- layer 1: 256 -> 128 ----
    mfma_gemm_kernel<256, 128, false><<<GEMM_BLOCKS, 512, 0, stream>>>(x, Wt1, xwb, N);
    gather_kernel<128, 1, 2, true><<<(N + 3) / 4, 256, 0, stream>>>(xwb, row_ptr, deg, pack, dinv, b1, act, N);
    // ---- layer 2: 128 -> 64 ----
    mfma_gemm_kernel<128, 64, true><<<GEMM_BLOCKS, 512, 0, stream>>>(act, Wt2, xwb, N);
    gather_kernel<64, 1, 1, true><<<(N + 3) / 4, 256, 0, stream>>>(xwb, row_ptr, deg, pack, dinv, b2, act, N);
    // ---- layer 3: 64 -> 32 ----
    mfma_gemm_kernel<64, 32, true><<<GEMM_BLOCKS, 512, 0, stream>>>(act, Wt3, xwb, N);
    gather_kernel<32, 2, 1, false><<<(N + 7) / 8, 256, 0, stream>>>(xwb, row_ptr, deg, pack, dinv, b3, out, N);
}

// Round 6
// 237.211 us; speedup vs baseline: 3.6923x; 1.1068x over previous
//
#include <hip/hip_runtime.h>
#include <hip/hip_bf16.h>
#include <math.h>

typedef __attribute__((ext_vector_type(8))) short s16x8;
typedef __attribute__((ext_vector_type(4))) float f32x4;

__device__ __forceinline__ unsigned short f2bf(float f) {
    unsigned int u = __float_as_uint(f);
    u += 0x7fffu + ((u >> 16) & 1u);
    return (unsigned short)(u >> 16);
}

__device__ __forceinline__ unsigned int pk2bf(float a, float b) {
    __hip_bfloat162 h = __float22bfloat162_rn(make_float2(a, b));
    return *(unsigned int*)&h;
}

// ---------------- small utility kernels ----------------

__global__ void zero_int_kernel(int* p, int n) {
    int i = blockIdx.x * blockDim.x + threadIdx.x;
    if (i < n) p[i] = 0;
}

__global__ void count_deg_kernel(const int* __restrict__ dst, int* deg, int E) {
    int i = blockIdx.x * blockDim.x + threadIdx.x;
    if (i < E) atomicAdd(&deg[dst[i]], 1);
}

// all three weights: W[K][N] fp32 -> Wt[N][K+8] bf16
__global__ void conv_w3_kernel(const float* __restrict__ W1, const float* __restrict__ W2,
                               const float* __restrict__ W3, unsigned short* __restrict__ Wt1,
                               unsigned short* __restrict__ Wt2, unsigned short* __restrict__ Wt3) {
    int i = blockIdx.x * blockDim.x + threadIdx.x;
    if (i < 32768) {                       // 256x128
        int k = i >> 7, n = i & 127;
        Wt1[(size_t)n * 264 + k] = f2bf(W1[i]);
    } else if (i < 40960) {                // 128x64
        int j = i - 32768, k = j >> 6, n = j & 63;
        Wt2[(size_t)n * 136 + k] = f2bf(W2[j]);
    } else if (i < 43008) {                // 64x32
        int j = i - 40960, k = j >> 5, n = j & 31;
        Wt3[(size_t)n * 72 + k] = f2bf(W3[j]);
    }
}

// ---------------- exclusive scan of deg -> row_ptr (+ dinv) ----------------

__global__ __launch_bounds__(256) void scan1_kernel(const int* __restrict__ deg,
                                                    int* __restrict__ row_ptr,
                                                    int* __restrict__ blockSums,
                                                    float* __restrict__ dinv, int n) {
    __shared__ int sm[256];
    int t = threadIdx.x;
    int i = blockIdx.x * 512 + 2 * t;
    int v0 = 0, v1 = 0;
    if (i < n) { v0 = deg[i]; v1 = deg[i + 1]; }  // n even
    if (i < n) {
        dinv[i] = rsqrtf((float)v0 + 1.0f);
        dinv[i + 1] = rsqrtf((float)v1 + 1.0f);
    }
    int ts = v0 + v1;
    sm[t] = ts;
    __syncthreads();
    for (int off = 1; off < 256; off <<= 1) {
        int u = (t >= off) ? sm[t - off] : 0;
        __syncthreads();
        sm[t] += u;
        __syncthreads();
    }
    int excl = sm[t] - ts;
    if (i < n) { row_ptr[i] = excl; row_ptr[i + 1] = excl + v0; }
    if (t == 255) blockSums[blockIdx.x] = sm[255];
}

__global__ __launch_bounds__(256) void scan2_kernel(const int* __restrict__ blockSums,
                                                    int* __restrict__ blockOffs, int nb) {
    __shared__ int sm[256];
    int t = threadIdx.x;
    int v = (t < nb) ? blockSums[t] : 0;
    sm[t] = v;
    __syncthreads();
    for (int off = 1; off < 256; off <<= 1) {
        int u = (t >= off) ? sm[t - off] : 0;
        __syncthreads();
        sm[t] += u;
        __syncthreads();
    }
    blockOffs[t] = sm[t] - v;
}

__global__ __launch_bounds__(256) void scan3_kernel(int* __restrict__ row_ptr,
                                                    int* __restrict__ cursor,
                                                    const int* __restrict__ blockOffs, int n) {
    int t = threadIdx.x;
    int i = blockIdx.x * 512 + 2 * t;
    int off = blockOffs[blockIdx.x];
    if (i < n) {
        int a = row_ptr[i] + off;
        int b = row_ptr[i + 1] + off;
        row_ptr[i] = a; cursor[i] = a;
        row_ptr[i + 1] = b; cursor[i + 1] = b;
    }
}

// ---------------- CSR fill: pack (src, coef) per edge, grouped by dst ----------------

__global__ void fill_kernel(const int* __restrict__ src, const int* __restrict__ dst,
                            const float* __restrict__ dinv, int* __restrict__ cursor,
                            int2* __restrict__ pack, int E) {
    int e = blockIdx.x * blockDim.x + threadIdx.x;
    if (e < E) {
        int s = src[e], d = dst[e];
        int pos = atomicAdd(&cursor[d], 1);
        pack[pos] = make_int2(s, __float_as_int(dinv[s] * dinv[d]));
    }
}

// ---------------- bf16 MFMA GEMM: C_bf16[M,N] = A[M,K] @ Wt_bf16 ----------------
// Wt pre-transposed [N][K+8] bf16, whole W staged in LDS once (no K-loop barrier).
// 512 threads = 8 waves, BM = 256 rows (32/wave). A is fp32 (cvt in-register) or bf16.

__device__ __forceinline__ s16x8 cvt8(const float4& u, const float4& v) {
    union { unsigned int w[4]; s16x8 s; } cb;
    cb.w[0] = pk2bf(u.x, u.y);
    cb.w[1] = pk2bf(u.z, u.w);
    cb.w[2] = pk2bf(v.x, v.y);
    cb.w[3] = pk2bf(v.z, v.w);
    return cb.s;
}

template <int K, int N, bool ABF16>
__global__ __launch_bounds__(512) void mfma_gemm_kernel(const void* __restrict__ Av,
                                                        const unsigned short* __restrict__ Bt,
                                                        unsigned short* __restrict__ C, int M) {
    constexpr int KP = K + 8;
    constexpr int KSTEPS = K / 32;
    constexpr int NFRAG = N / 16;
    constexpr int BYTES = N * KP * 2;
    __shared__ unsigned short Blds[N * KP];

    int tid = threadIdx.x;
    for (int off = tid * 16; off < BYTES; off += 512 * 16)
        *(float4*)((char*)Blds + off) = *(const float4*)((const char*)Bt + off);
    __syncthreads();

    int wv = tid >> 6, lane = tid & 63;
    int r0 = blockIdx.x * 256 + wv * 32;
    int lr = lane & 15, kg = lane >> 4;
    int ra = min(r0 + lr, M - 1);
    int rb = min(r0 + 16 + lr, M - 1);

    f32x4 acc[2][NFRAG] = {};

    const float* a0f = nullptr; const float* a1f = nullptr;
    const unsigned short* a0h = nullptr; const unsigned short* a1h = nullptr;
    if constexpr (ABF16) {
        a0h = (const unsigned short*)Av + (size_t)ra * K + kg * 8;
        a1h = (const unsigned short*)Av + (size_t)rb * K + kg * 8;
    } else {
        a0f = (const float*)Av + (size_t)ra * K + kg * 8;
        a1f = (const float*)Av + (size_t)rb * K + kg * 8;
    }

#pragma unroll
    for (int ks = 0; ks < KSTEPS; ++ks) {
        s16x8 a0, a1;
        if constexpr (ABF16) {
            a0 = *(const s16x8*)(a0h + ks * 32);
            a1 = *(const s16x8*)(a1h + ks * 32);
        } else {
            float4 u = *(const float4*)(a0f + ks * 32);
            float4 v = *(const float4*)(a0f + ks * 32 + 4);
            a0 = cvt8(u, v);
            u = *(const float4*)(a1f + ks * 32);
            v = *(const float4*)(a1f + ks * 32 + 4);
            a1 = cvt8(u, v);
        }
#pragma unroll
        for (int ni = 0; ni < NFRAG; ++ni) {
            const s16x8 b = *(const s16x8*)&Blds[(ni * 16 + lr) * KP + kg * 8 + ks * 32];
            acc[0][ni] = __builtin_amdgcn_mfma_f32_16x16x32_bf16(a0, b, acc[0][ni], 0, 0, 0);
            acc[1][ni] = __builtin_amdgcn_mfma_f32_16x16x32_bf16(a1, b, acc[1][ni], 0, 0, 0);
        }
    }

    // C/D layout: col = lane&15, row = (lane>>4)*4 + reg
    int rbase = kg * 4;
#pragma unroll
    for (int mi = 0; mi < 2; ++mi) {
#pragma unroll
        for (int r = 0; r < 4; ++r) {
            int row = r0 + mi * 16 + rbase + r;
            if (row < M) {
#pragma unroll
                for (int ni = 0; ni < NFRAG; ++ni)
                    C[(size_t)row * N + ni * 16 + lr] = f2bf(acc[mi][ni][r]);
            }
        }
    }
}

// ---------------- fused gather: out = relu(sum(coef*xw[src]) + dinv^2*xw[n] + b) ----------------
// GPW dst-nodes per wave, 64/GPW lanes each, VPL bf16 values per lane.

template <int F, int GPW, int VPL, bool OUT_BF16>
__global__ __launch_bounds__(256) void gather_kernel(const unsigned short* __restrict__ xw,
                                                     const int* __restrict__ row_ptr,
                                                     const int* __restrict__ deg,
                                                     const int2* __restrict__ pack,
                                                     const float* __restrict__ dinv,
                                                     const float* __restrict__ bias,
                                                     void* __restrict__ outv, int N) {
    constexpr int LPG = 64 / GPW;
    static_assert(LPG * VPL == F, "lane layout must cover F");
    int wave = blockIdx.x * 4 + (threadIdx.x >> 6);
    int lane = threadIdx.x & 63;
    int wid = wave * GPW + lane / LPG;
    int gl = lane % LPG;
    if (wid >= N) return;
    const int f0 = gl * VPL;

    auto loadrow = [&](const unsigned short* r, float* y) {
        if constexpr (VPL == 4) {
            uint2 b = *(const uint2*)(r + f0);
            y[0] = __uint_as_float(b.x << 16);
            y[1] = __uint_as_float(b.x & 0xffff0000u);
            y[2] = __uint_as_float(b.y << 16);
            y[3] = __uint_as_float(b.y & 0xffff0000u);
        } else {
            unsigned int b = *(const unsigned int*)(r + f0);
            y[0] = __uint_as_float(b << 16);
            y[1] = __uint_as_float(b & 0xffff0000u);
        }
    };

    float dn = dinv[wid];
    float acc[VPL], y0[VPL], y1[VPL], y2[VPL], y3[VPL];
    loadrow(xw + (size_t)wid * F, y0);
#pragma unroll
    for (int q = 0; q < VPL; ++q) acc[q] = y0[q] * dn * dn;

    int beg = row_ptr[wid];
    int cnt = deg[wid];
    int j = 0;
    for (; j + 3 < cnt; j += 4) {
        int2 p0 = pack[beg + j];
        int2 p1 = pack[beg + j + 1];
        int2 p2 = pack[beg + j + 2];
        int2 p3 = pack[beg + j + 3];
        loadrow(xw + (size_t)p0.x * F, y0);
        loadrow(xw + (size_t)p1.x * F, y1);
        loadrow(xw + (size_t)p2.x * F, y2);
        loadrow(xw + (size_t)p3.x * F, y3);
        float c0 = __int_as_float(p0.y), c1 = __int_as_float(p1.y);
        float c2 = __int_as_float(p2.y), c3 = __int_as_float(p3.y);
#pragma unroll
        for (int q = 0; q < VPL; ++q)
            acc[q] += y0[q] * c0 + y1[q] * c1 + y2[q] * c2 + y3[q] * c3;
    }
    for (; j < cnt; ++j) {
        int2 p0 = pack[beg + j];
        loadrow(xw + (size_t)p0.x * F, y0);
        float c0 = __int_as_float(p0.y);
#pragma unroll
        for (int q = 0; q < VPL; ++q) acc[q] += y0[q] * c0;
    }

    float o[VPL];
#pragma unroll
    for (int q = 0; q < VPL; ++q) o[q] = fmaxf(acc[q] + bias[f0 + q], 0.0f);

    if constexpr (OUT_BF16) {
        unsigned short* op = (unsigned short*)outv + (size_t)wid * F + f0;
        if constexpr (VPL == 4) {
            *(uint2*)op = make_uint2(pk2bf(o[0], o[1]), pk2bf(o[2], o[3]));
        } else {
            *(unsigned int*)op = pk2bf(o[0], o[1]);
        }
    } else {
        float* op = (float*)outv + (size_t)wid * F + f0;
        if constexpr (VPL == 4) {
            *(float4*)op = make_float4(o[0], o[1], o[2], o[3]);
        } else {
            *(float2*)op = make_float2(o[0], o[1]);
        }
    }
}

// ---------------- launch ----------------

extern "C" void kernel_launch(void* const* d_in, const int* in_sizes, int n_in,
                              void* d_out, int out_size, void* d_ws, size_t ws_size,
                              hipStream_t stream) {
    const float* x = (const float*)d_in[0];
    const int* edge = (const int*)d_in[1];
    const float* W1 = (const float*)d_in[2];
    const float* b1 = (const float*)d_in[3];
    const float* W2 = (const float*)d_in[4];
    const float* b2 = (const float*)d_in[5];
    const float* W3 = (const float*)d_in[6];
    const float* b3 = (const float*)d_in[7];

    const int C_IN = 256, H1 = 128;
    const int N = in_sizes[0] / C_IN;   // 100000
    const int E = in_sizes[1] / 2;      // 800000
    const int* srcp = edge;
    const int* dstp = edge + E;

    // ---- workspace carve ----
    char* p = (char*)d_ws;
    size_t o = 0;
    auto alloc = [&](size_t bytes) -> void* {
        void* r = p + o;
        o = (o + bytes + 255) & ~(size_t)255;
        return r;
    };
    float* dinv      = (float*)alloc((size_t)N * 4);
    int*   deg       = (int*)alloc((size_t)N * 4);
    int*   row_ptr   = (int*)alloc((size_t)N * 4);
    int*   cursor    = (int*)alloc((size_t)N * 4);
    int*   blockSums = (int*)alloc(1024);
    int*   blockOffs = (int*)alloc(1024);
    int2*  pack      = (int2*)alloc((size_t)E * 8);
    unsigned short* Wt1 = (unsigned short*)alloc((size_t)128 * 264 * 2);
    unsigned short* Wt2 = (unsigned short*)alloc((size_t)64 * 136 * 2);
    unsigned short* Wt3 = (unsigned short*)alloc((size_t)32 * 72 * 2);
    unsigned short* xwb = (unsigned short*)alloc((size_t)N * H1 * 2);  // bf16 xw
    unsigned short* act = (unsigned short*)alloc((size_t)N * H1 * 2);  // bf16 activations
    float* out = (float*)d_out;

    const int NB = (N + 511) / 512;  // 196 <= 256

    // ---- CSR build + weight transpose/convert ----
    zero_int_kernel<<<(N + 255) / 256, 256, 0, stream>>>(deg, N);
    count_deg_kernel<<<(E + 255) / 256, 256, 0, stream>>>(dstp, deg, E);
    scan1_kernel<<<NB, 256, 0, stream>>>(deg, row_ptr, blockSums, dinv, N);
    scan2_kernel<<<1, 256, 0, stream>>>(blockSums, blockOffs, NB);
    scan3_kernel<<<NB, 256, 0, stream>>>(row_ptr, cursor, blockOffs, N);
    fill_kernel<<<(E + 255) / 256, 256, 0, stream>>>(srcp, dstp, dinv, cursor, pack, E);
    conv_w3_kernel<<<(43008 + 255) / 256, 256, 0, stream>>>(W1, W2, W3, Wt1, Wt2, Wt3);

    const int GEMM_BLOCKS = (N + 255) / 256;

    // ---- layer 1: 256 -> 128 ----
    mfma_gemm_kernel<256, 128, false><<<GEMM_BLOCKS, 512, 0, stream>>>(x, Wt1, xwb, N);
    gather_kernel<128, 2, 4, true><<<(N + 7) / 8, 256, 0, stream>>>(xwb, row_ptr, deg, pack, dinv, b1, act, N);
    // ---- layer 2: 128 -> 64 ----
    mfma_gemm_kernel<128, 64, true><<<GEMM_BLOCKS, 512, 0, stream>>>(act, Wt2, xwb, N);
    gather_kernel<64, 2, 2, true><<<(N + 7) / 8, 256, 0, stream>>>(xwb, row_ptr, deg, pack, dinv, b2, act, N);
    // ---- layer 3: 64 -> 32 ----
    mfma_gemm_kernel<64, 32, true><<<GEMM_BLOCKS, 512, 0, stream>>>(act, Wt3, xwb, N);
    gather_kernel<32, 4, 2, false><<<(N + 15) / 16, 256, 0, stream>>>(xwb, row_ptr, deg, pack, dinv, b3, out, N);
}